// Round 1
// baseline (6127.403 us; speedup 1.0000x reference)
//
#include <hip/hip_runtime.h>

#define TT 64
#define BB 32
#define SS 1024
#define HH 256
#define AA 64
#define VV 32000

typedef unsigned short u16;
typedef __attribute__((ext_vector_type(4))) float f32x4;
typedef __attribute__((ext_vector_type(8))) short s16x8;
typedef __attribute__((ext_vector_type(8))) unsigned short u16x8;

__device__ __forceinline__ float b2f(u16 u) {
  union { unsigned int u; float f; } c; c.u = ((unsigned int)u) << 16; return c.f;
}
__device__ __forceinline__ u16 f2b(float x) {
  union { float f; unsigned int u; } c; c.f = x;
  unsigned int r = c.u + 0x7FFFu + ((c.u >> 16) & 1u);
  return (u16)(r >> 16);
}
__device__ __forceinline__ float aloadf(const float* p) {
  return __hip_atomic_load(p, __ATOMIC_RELAXED, __HIP_MEMORY_SCOPE_AGENT);
}
__device__ __forceinline__ void astoref(float* p, float v) {
  __hip_atomic_store(p, v, __ATOMIC_RELAXED, __HIP_MEMORY_SCOPE_AGENT);
}

// ---------------------------------------------------------------- conversions
__global__ void conv_bf(u16* __restrict__ dst, const float* __restrict__ src,
                        int n, int shift, int srcStride, int srcOff) {
  int i = blockIdx.x * 256 + threadIdx.x;
  if (i < n) {
    int r = i >> shift, c = i & ((1 << shift) - 1);
    dst[i] = f2b(src[(size_t)r * srcStride + srcOff + c]);
  }
}

__global__ void gather_emb(u16* __restrict__ dst, const float* __restrict__ emb,
                           const int* __restrict__ yin, int n) {
  int i = blockIdx.x * 256 + threadIdx.x;
  if (i < n) {
    int row = i >> 8, c = i & 255;
    int tok = yin[row];
    dst[i] = f2b(emb[(size_t)tok * HH + c]);
  }
}

__global__ void concat_hoc(u16* __restrict__ dst, const float* __restrict__ h_all,
                           const float* __restrict__ ctx_all, int n) {
  int i = blockIdx.x * 256 + threadIdx.x;
  if (i < n) {
    int row = i >> 9, c = i & 511;
    float v = (c < HH) ? h_all[(size_t)row * HH + c] : ctx_all[(size_t)row * HH + (c - HH)];
    dst[i] = f2b(v);
  }
}

// ---------------------------------------------------------------- generic GEMM
// C[M,N] = act(A[M,K] @ W[N,K]^T + bias), A bf16 (AF32=0) or f32 (AF32=1),
// W bf16. Optional per-(row, n-tile) online-softmax partials into stats.
template <int AF32>
__global__ __launch_bounds__(256) void gemm_k(
    const void* __restrict__ Ap, const u16* __restrict__ W,
    const float* __restrict__ bias, void* __restrict__ Out,
    const int M, const int N, const int K, const int act, const int out_bf,
    float2* __restrict__ stats, const int ntiles) {
  __shared__ u16 sA[64 * 40];
  __shared__ u16 sB[64 * 40];
  const int tid = threadIdx.x;
  const int mt = blockIdx.x, nt = blockIdx.y;
  const int m0 = mt * 64, n0 = nt * 64;
  const int wave = tid >> 6, lane = tid & 63;
  const int quad = lane >> 4, l16 = lane & 15;
  const int r = tid >> 2, cc = (tid & 3) * 8;
  f32x4 acc[4] = {{0.f,0.f,0.f,0.f},{0.f,0.f,0.f,0.f},{0.f,0.f,0.f,0.f},{0.f,0.f,0.f,0.f}};

  for (int kk = 0; kk < K; kk += 32) {
    if (AF32) {
      const float* A = (const float*)Ap;
      const float* src = A + (size_t)(m0 + r) * K + kk + cc;
      const float4 v0 = *(const float4*)src;
      const float4 v1 = *(const float4*)(src + 4);
      u16* d = &sA[r * 40 + cc];
      d[0] = f2b(v0.x); d[1] = f2b(v0.y); d[2] = f2b(v0.z); d[3] = f2b(v0.w);
      d[4] = f2b(v1.x); d[5] = f2b(v1.y); d[6] = f2b(v1.z); d[7] = f2b(v1.w);
    } else {
      const u16* A = (const u16*)Ap;
      *(u16x8*)&sA[r * 40 + cc] = *(const u16x8*)(A + (size_t)(m0 + r) * K + kk + cc);
    }
    *(u16x8*)&sB[r * 40 + cc] = *(const u16x8*)(W + (size_t)(n0 + r) * K + kk + cc);
    __syncthreads();
    const s16x8 af = *(const s16x8*)&sA[(wave * 16 + l16) * 40 + quad * 8];
#pragma unroll
    for (int ns = 0; ns < 4; ++ns) {
      const s16x8 bf = *(const s16x8*)&sB[(ns * 16 + l16) * 40 + quad * 8];
      acc[ns] = __builtin_amdgcn_mfma_f32_16x16x32_bf16(af, bf, acc[ns], 0, 0, 0);
    }
    __syncthreads();
  }

  float vv[4][4];
#pragma unroll
  for (int ns = 0; ns < 4; ++ns) {
#pragma unroll
    for (int rr = 0; rr < 4; ++rr) {
      const int row = m0 + wave * 16 + quad * 4 + rr;
      const int col = n0 + ns * 16 + l16;
      float v = acc[ns][rr] + bias[col];
      if (act == 1) v = fmaxf(v, 0.f);
      else if (act == 2) v = tanhf(v);
      vv[ns][rr] = v;
      if (out_bf) ((u16*)Out)[(size_t)row * N + col] = f2b(v);
      else ((float*)Out)[(size_t)row * N + col] = v;
    }
  }
  if (stats) {
#pragma unroll
    for (int rr = 0; rr < 4; ++rr) {
      float mx = fmaxf(fmaxf(vv[0][rr], vv[1][rr]), fmaxf(vv[2][rr], vv[3][rr]));
#pragma unroll
      for (int off = 1; off < 16; off <<= 1) mx = fmaxf(mx, __shfl_xor(mx, off));
      float se = expf(vv[0][rr] - mx) + expf(vv[1][rr] - mx) +
                 expf(vv[2][rr] - mx) + expf(vv[3][rr] - mx);
#pragma unroll
      for (int off = 1; off < 16; off <<= 1) se += __shfl_xor(se, off);
      if (l16 == 0) {
        const int row = m0 + wave * 16 + quad * 4 + rr;
        stats[(size_t)row * ntiles + nt] = make_float2(mx, se);
      }
    }
  }
}

// ---------------------------------------------------------------- scan kernel
// 256 blocks: b = blk>>3 (batch row), k = blk&7 (S-slice / h-slice).
// Two flag syncs per step, scoped to the 8 blocks of each b.
__global__ __launch_bounds__(256, 1) void scan_kernel(
    const float* __restrict__ y_enc, const u16* __restrict__ Wihc,
    const float* __restrict__ gw_hh, const float* __restrict__ gb_hh,
    const u16* __restrict__ f1w1b, const float* __restrict__ f1_b1,
    const float* __restrict__ f1_w2, const float* __restrict__ f1_b2,
    const u16* __restrict__ c2bf, const float* __restrict__ gi_emb,
    float* __restrict__ h_all, float* __restrict__ ctx_all,
    float* __restrict__ qp, float* __restrict__ part_m, float* __restrict__ part_l,
    float* __restrict__ part_ctx, int* __restrict__ cnt_h, int* __restrict__ cnt_att) {
  __shared__ u16 sYenc[128 * HH];   // 64 KB : y_enc[s-slice, b, :]
  __shared__ u16 sWhh[96 * HH];     // 48 KB : W_hh rows (r,z,n) of h-slice
  __shared__ u16 sF1w2[AA * HH];    // 32 KB
  __shared__ float sH[HH], sCtx[HH], sQ[HH];
  __shared__ float sHnew[32];
  __shared__ float sC1[AA];
  __shared__ float sP[128];
  __shared__ float sRed[32];

  const int tid = threadIdx.x;
  const int b = blockIdx.x >> 3, k = blockIdx.x & 7;

  for (int idx = tid; idx < 128 * HH; idx += 256) {
    int si = idx >> 8, m = idx & 255;
    sYenc[idx] = f2b(y_enc[((size_t)(k * 128 + si) * BB + b) * HH + m]);
  }
  for (int idx = tid; idx < 96 * HH; idx += 256) {
    int row = idx >> 8, m = idx & 255;
    int g = row >> 5, jj = row & 31;
    sWhh[idx] = f2b(gw_hh[(size_t)(g * HH + k * 32 + jj) * HH + m]);
  }
  for (int idx = tid; idx < AA * HH; idx += 256) sF1w2[idx] = f2b(f1_w2[idx]);
  if (tid < HH) { sH[tid] = 0.f; sCtx[tid] = 0.f; }
  __syncthreads();

  for (int t = 0; t < TT; ++t) {
    // ---------- Phase A: GRU h-slice ----------
    {
      const int jj = tid >> 3, p = tid & 7;
      const int jg = k * 32 + jj;
      const int mbase = p * 32;
      const u16* wbase = Wihc + (size_t)jg * HH + mbase;
      const u16* lbase = &sWhh[jj * HH + mbase];
      float ar = 0.f, az = 0.f, an = 0.f, br = 0.f, bz = 0.f, bn = 0.f;
#pragma unroll
      for (int ii = 0; ii < 8; ++ii) {
        const int i4 = ((ii + p) & 7) * 4;
        const float4 cm = *(const float4*)&sCtx[mbase + i4];
        const float4 hm = *(const float4*)&sH[mbase + i4];
        ushort4 wr = *(const ushort4*)(wbase + i4);
        ushort4 wz = *(const ushort4*)(wbase + 65536 + i4);
        ushort4 wn = *(const ushort4*)(wbase + 131072 + i4);
        ar += cm.x * b2f(wr.x) + cm.y * b2f(wr.y) + cm.z * b2f(wr.z) + cm.w * b2f(wr.w);
        az += cm.x * b2f(wz.x) + cm.y * b2f(wz.y) + cm.z * b2f(wz.z) + cm.w * b2f(wz.w);
        an += cm.x * b2f(wn.x) + cm.y * b2f(wn.y) + cm.z * b2f(wn.z) + cm.w * b2f(wn.w);
        ushort4 hr = *(const ushort4*)(lbase + i4);
        ushort4 hz = *(const ushort4*)(lbase + 32 * HH + i4);
        ushort4 hn = *(const ushort4*)(lbase + 64 * HH + i4);
        br += hm.x * b2f(hr.x) + hm.y * b2f(hr.y) + hm.z * b2f(hr.z) + hm.w * b2f(hr.w);
        bz += hm.x * b2f(hz.x) + hm.y * b2f(hz.y) + hm.z * b2f(hz.z) + hm.w * b2f(hz.w);
        bn += hm.x * b2f(hn.x) + hm.y * b2f(hn.y) + hm.z * b2f(hn.z) + hm.w * b2f(hn.w);
      }
#pragma unroll
      for (int off = 1; off < 8; off <<= 1) {
        ar += __shfl_xor(ar, off); az += __shfl_xor(az, off); an += __shfl_xor(an, off);
        br += __shfl_xor(br, off); bz += __shfl_xor(bz, off); bn += __shfl_xor(bn, off);
      }
      if (p == 0) {
        const float* ge = gi_emb + (size_t)(t * BB + b) * 768;
        float gr = ar + ge[jg];
        float gz = az + ge[256 + jg];
        float gn = an + ge[512 + jg];
        float hr2 = br + gb_hh[jg];
        float hz2 = bz + gb_hh[256 + jg];
        float hn2 = bn + gb_hh[512 + jg];
        float r_ = 1.f / (1.f + expf(-(gr + hr2)));
        float z_ = 1.f / (1.f + expf(-(gz + hz2)));
        float n_ = tanhf(gn + r_ * hn2);
        float hnw = (1.f - z_) * n_ + z_ * sH[jg];
        sHnew[jj] = hnw;
        astoref(&h_all[(size_t)(t * BB + b) * HH + jg], hnw);
      }
    }
    __syncthreads();
    // layer1 partial contribution of this h-slice (linear, pre-relu)
    {
      float q = 0.f;
      const u16* wrow = f1w1b + (size_t)tid * HH + k * 32;
#pragma unroll
      for (int j4 = 0; j4 < 32; j4 += 4) {
        ushort4 w4 = *(const ushort4*)(wrow + j4);
        q += sHnew[j4] * b2f(w4.x) + sHnew[j4 + 1] * b2f(w4.y) +
             sHnew[j4 + 2] * b2f(w4.z) + sHnew[j4 + 3] * b2f(w4.w);
      }
      astoref(&qp[(size_t)(b * 8 + k) * HH + tid], q);
    }
    __syncthreads();
    __threadfence();
    if (tid == 0) {
      __hip_atomic_fetch_add(&cnt_h[t * BB + b], 1, __ATOMIC_RELEASE, __HIP_MEMORY_SCOPE_AGENT);
      while (__hip_atomic_load(&cnt_h[t * BB + b], __ATOMIC_ACQUIRE, __HIP_MEMORY_SCOPE_AGENT) < 8)
        __builtin_amdgcn_s_sleep(4);
    }
    __syncthreads();
    __threadfence();
    // ---------- Phase A': gather h, layer1 sum+relu, c1 ----------
    sH[tid] = aloadf(&h_all[(size_t)(t * BB + b) * HH + tid]);
    {
      float qq = f1_b1[tid];
#pragma unroll
      for (int k2 = 0; k2 < 8; ++k2) qq += aloadf(&qp[(size_t)(b * 8 + k2) * HH + tid]);
      sQ[tid] = fmaxf(qq, 0.f);
    }
    __syncthreads();
    {
      const int a = tid >> 2, p4 = tid & 3;
      float s = 0.f;
      const u16* wa = &sF1w2[a * HH];
#pragma unroll
      for (int ii = 0; ii < 16; ++ii) {
        const int i4 = (((ii + a) & 15) * 4) + p4 * 64;
        ushort4 w4 = *(const ushort4*)(wa + i4);
        s += sQ[i4] * b2f(w4.x) + sQ[i4 + 1] * b2f(w4.y) +
             sQ[i4 + 2] * b2f(w4.z) + sQ[i4 + 3] * b2f(w4.w);
      }
      s += __shfl_xor(s, 1);
      s += __shfl_xor(s, 2);
      if (p4 == 0) sC1[a] = tanhf(s + f1_b2[a]);
    }
    __syncthreads();
    // ---------- Phase B: scores + online softmax + ctx partial ----------
    if (tid < 128) {
      const int sg = k * 128 + tid;
      const u16* c2r = c2bf + (size_t)(sg * BB + b) * AA;
      float sc = 0.f;
#pragma unroll
      for (int a4 = 0; a4 < AA; a4 += 4) {
        ushort4 c4 = *(const ushort4*)(c2r + a4);
        sc += sC1[a4] * b2f(c4.x) + sC1[a4 + 1] * b2f(c4.y) +
              sC1[a4 + 2] * b2f(c4.z) + sC1[a4 + 3] * b2f(c4.w);
      }
      sP[tid] = sc;
    }
    __syncthreads();
    {
      float v = (tid < 64) ? fmaxf(sP[tid], sP[tid + 64]) : -3e38f;
#pragma unroll
      for (int off = 1; off < 64; off <<= 1) v = fmaxf(v, __shfl_xor(v, off));
      if (tid == 0) sRed[0] = v;
    }
    __syncthreads();
    const float mloc = sRed[0];
    {
      float e = 0.f;
      if (tid < 128) { e = expf(sP[tid] - mloc); sP[tid] = e; }
#pragma unroll
      for (int off = 1; off < 64; off <<= 1) e += __shfl_xor(e, off);
      if ((tid & 63) == 0) sRed[1 + (tid >> 6)] = e;
    }
    __syncthreads();
    {
      float accm = 0.f;
#pragma unroll 8
      for (int si = 0; si < 128; ++si) accm += sP[si] * b2f(sYenc[si * HH + tid]);
      astoref(&part_ctx[(size_t)(b * 8 + k) * HH + tid], accm);
      if (tid == 0) {
        astoref(&part_m[b * 8 + k], mloc);
        astoref(&part_l[b * 8 + k], sRed[1] + sRed[2] + sRed[3] + sRed[4]);
      }
    }
    __syncthreads();
    __threadfence();
    if (tid == 0) {
      __hip_atomic_fetch_add(&cnt_att[t * BB + b], 1, __ATOMIC_RELEASE, __HIP_MEMORY_SCOPE_AGENT);
      while (__hip_atomic_load(&cnt_att[t * BB + b], __ATOMIC_ACQUIRE, __HIP_MEMORY_SCOPE_AGENT) < 8)
        __builtin_amdgcn_s_sleep(4);
    }
    __syncthreads();
    __threadfence();
    // ---------- Phase B': combine 8 online-softmax partials ----------
    if (tid < 8) {
      sRed[16 + tid] = aloadf(&part_m[b * 8 + tid]);
      sRed[24 + tid] = aloadf(&part_l[b * 8 + tid]);
    }
    __syncthreads();
    {
      float M = -3e38f;
#pragma unroll
      for (int k2 = 0; k2 < 8; ++k2) M = fmaxf(M, sRed[16 + k2]);
      float L = 0.f;
      float w8[8];
#pragma unroll
      for (int k2 = 0; k2 < 8; ++k2) {
        float e = expf(sRed[16 + k2] - M);
        w8[k2] = e;
        L += sRed[24 + k2] * e;
      }
      const float inv = 1.f / L;
      float cx = 0.f;
#pragma unroll
      for (int k2 = 0; k2 < 8; ++k2)
        cx += w8[k2] * aloadf(&part_ctx[(size_t)(b * 8 + k2) * HH + tid]);
      cx *= inv;
      sCtx[tid] = cx;
      ctx_all[(size_t)(t * BB + b) * HH + tid] = cx;
    }
    __syncthreads();
  }
}

// ---------------------------------------------------------------- loss
__global__ __launch_bounds__(256) void loss_rows(
    const float2* __restrict__ stats, const float* __restrict__ preds,
    const int* __restrict__ tgt, float* __restrict__ accum, int ntiles) {
  const int row = blockIdx.x, tid = threadIdx.x;
  float m = -3e38f, l = 0.f;
  for (int j = tid; j < ntiles; j += 256) {
    float2 s = stats[(size_t)row * ntiles + j];
    if (s.x > m) { l = l * expf(m - s.x) + s.y; m = s.x; }
    else l += s.y * expf(s.x - m);
  }
  __shared__ float sm[256], sl[256];
  sm[tid] = m; sl[tid] = l;
  __syncthreads();
  for (int off = 128; off; off >>= 1) {
    if (tid < off) {
      float m2 = sm[tid + off], l2 = sl[tid + off];
      float M = fmaxf(sm[tid], m2);
      sl[tid] = sl[tid] * expf(sm[tid] - M) + l2 * expf(m2 - M);
      sm[tid] = M;
    }
    __syncthreads();
  }
  if (tid == 0) {
    int t = tgt[row];
    float lse = sm[0] + logf(sl[0]);
    float nll = lse - preds[(size_t)row * VV + t];
    if (t != 0) {
      atomicAdd(&accum[0], nll);
      atomicAdd(&accum[1], 1.f);
    }
  }
}

__global__ void finalize_k(const float* __restrict__ accum, float* __restrict__ out) {
  out[0] = accum[0] / fmaxf(accum[1], 1.f);
}

// ---------------------------------------------------------------- launcher
extern "C" void kernel_launch(void* const* d_in, const int* in_sizes, int n_in,
                              void* d_out, int out_size, void* d_ws, size_t ws_size,
                              hipStream_t stream) {
  (void)in_sizes; (void)n_in; (void)out_size; (void)ws_size;
  const int* y_in = (const int*)d_in[0];
  const int* y_out = (const int*)d_in[1];
  const float* y_enc = (const float*)d_in[2];
  const float* emb = (const float*)d_in[4];
  const float* f1_w1 = (const float*)d_in[5];
  const float* f1_b1 = (const float*)d_in[6];
  const float* f1_w2 = (const float*)d_in[7];
  const float* f1_b2 = (const float*)d_in[8];
  const float* f2_w1 = (const float*)d_in[9];
  const float* f2_b1 = (const float*)d_in[10];
  const float* f2_w2 = (const float*)d_in[11];
  const float* f2_b2 = (const float*)d_in[12];
  const float* gw_ih = (const float*)d_in[13];
  const float* gb_ih = (const float*)d_in[14];
  const float* gw_hh = (const float*)d_in[15];
  const float* gb_hh = (const float*)d_in[16];
  const float* fc1_w = (const float*)d_in[17];
  const float* fc1_b = (const float*)d_in[18];
  const float* fc2_w = (const float*)d_in[19];
  const float* fc2_b = (const float*)d_in[20];
  float* out = (float*)d_out;

  char* w = (char*)d_ws;
  auto alloc = [&](size_t bytes) {
    char* p = w;
    w += (bytes + 255) & ~(size_t)255;
    return p;
  };
  int* cnt_h = (int*)alloc(TT * BB * 4);           // 8 KB
  int* cnt_att = (int*)alloc(TT * BB * 4);         // 8 KB
  float* accum = (float*)alloc(256);
  float* gi_emb = (float*)alloc((size_t)2048 * 768 * 4);
  float* h_all = (float*)alloc((size_t)2048 * HH * 4);
  float* ctx_all = (float*)alloc((size_t)2048 * HH * 4);
  float* qp = (float*)alloc((size_t)BB * 8 * HH * 4);
  float* part_m = (float*)alloc(1024);
  float* part_l = (float*)alloc(1024);
  float* part_ctx = (float*)alloc((size_t)BB * 8 * HH * 4);
  u16* c2_bf = (u16*)alloc((size_t)SS * BB * AA * 2);
  u16* Wihe = (u16*)alloc((size_t)768 * HH * 2);
  u16* Wihc = (u16*)alloc((size_t)768 * HH * 2);
  u16* f2w1b = (u16*)alloc((size_t)HH * HH * 2);
  u16* f2w2b = (u16*)alloc((size_t)AA * HH * 2);
  u16* f1w1b = (u16*)alloc((size_t)HH * HH * 2);
  u16* fc1wb = (u16*)alloc((size_t)HH * 512 * 2);
  u16* fc2wb = (u16*)alloc((size_t)VV * HH * 2);
  u16* aembb = (u16*)alloc((size_t)2048 * HH * 2);
  u16* z1 = (u16*)alloc((size_t)2048 * HH * 2);
  u16* hocb = (u16*)alloc((size_t)2048 * 512 * 2);
  char* tmp_region = alloc((size_t)32768 * 256 * 2);  // tmp1 (bf16), later stats
  u16* tmp1 = (u16*)tmp_region;
  float2* stats = (float2*)tmp_region;  // 2048*500*8 = 8.2MB <= 16.8MB

  hipMemsetAsync(d_ws, 0, TT * BB * 4 * 2 + 512, stream);  // counters + accum

  // weight conversions
  conv_bf<<<dim3(256), dim3(256), 0, stream>>>(f2w1b, f2_w1, 65536, 8, 256, 0);
  conv_bf<<<dim3(64), dim3(256), 0, stream>>>(f2w2b, f2_w2, 16384, 8, 256, 0);
  conv_bf<<<dim3(768), dim3(256), 0, stream>>>(Wihe, gw_ih, 196608, 8, 512, 0);
  conv_bf<<<dim3(768), dim3(256), 0, stream>>>(Wihc, gw_ih, 196608, 8, 512, 256);
  conv_bf<<<dim3(256), dim3(256), 0, stream>>>(f1w1b, f1_w1, 65536, 8, 256, 0);
  conv_bf<<<dim3(512), dim3(256), 0, stream>>>(fc1wb, fc1_w, 131072, 9, 512, 0);
  conv_bf<<<dim3(32000), dim3(256), 0, stream>>>(fc2wb, fc2_w, 8192000, 8, 256, 0);
  gather_emb<<<dim3(2048), dim3(256), 0, stream>>>(aembb, emb, y_in, 2048 * 256);

  // gi_emb = emb_gathered @ W_ih[:, :256]^T + b_ih   [2048, 768]
  gemm_k<0><<<dim3(32, 12), dim3(256), 0, stream>>>(
      aembb, Wihe, gb_ih, gi_emb, 2048, 768, 256, 0, 0, nullptr, 0);
  // tmp1 = relu(y_enc @ f2_w1^T + b1)   [32768, 256] bf16
  gemm_k<1><<<dim3(512, 4), dim3(256), 0, stream>>>(
      y_enc, f2w1b, f2_b1, tmp1, 32768, 256, 256, 1, 1, nullptr, 0);
  // c2 = tanh(tmp1 @ f2_w2^T + b2)   [32768, 64] bf16
  gemm_k<0><<<dim3(512, 1), dim3(256), 0, stream>>>(
      tmp1, f2w2b, f2_b2, c2_bf, 32768, 64, 256, 2, 1, nullptr, 0);

  // sequential scan: 64 steps, persistent blocks, per-b flag sync
  scan_kernel<<<dim3(256), dim3(256), 0, stream>>>(
      y_enc, Wihc, gw_hh, gb_hh, f1w1b, f1_b1, f1_w2, f1_b2, c2_bf, gi_emb,
      h_all, ctx_all, qp, part_m, part_l, part_ctx, cnt_h, cnt_att);

  // output head
  concat_hoc<<<dim3(4096), dim3(256), 0, stream>>>(hocb, h_all, ctx_all, 2048 * 512);
  gemm_k<0><<<dim3(32, 4), dim3(256), 0, stream>>>(
      hocb, fc1wb, fc1_b, z1, 2048, 256, 512, 1, 1, nullptr, 0);
  gemm_k<0><<<dim3(32, 500), dim3(256), 0, stream>>>(
      z1, fc2wb, fc2_b, out, 2048, VV, 256, 0, 0, stats, 500);

  // masked mean NLL from per-tile softmax stats
  loss_rows<<<dim3(2048), dim3(256), 0, stream>>>(stats, out, y_out, accum, 500);
  finalize_k<<<dim3(1), dim3(1), 0, stream>>>(accum, out + (size_t)TT * BB * VV);
}

// Round 2
// 1958.648 us; speedup vs baseline: 3.1284x; 3.1284x over previous
//
#include <hip/hip_runtime.h>

#define TT 64
#define BB 32
#define SS 1024
#define HH 256
#define AA 64
#define VV 32000

typedef unsigned short u16;
typedef __attribute__((ext_vector_type(4))) float f32x4;
typedef __attribute__((ext_vector_type(8))) short s16x8;
typedef __attribute__((ext_vector_type(8))) unsigned short u16x8;

__device__ __forceinline__ float b2f(u16 u) {
  union { unsigned int u; float f; } c; c.u = ((unsigned int)u) << 16; return c.f;
}
__device__ __forceinline__ u16 f2b(float x) {
  union { float f; unsigned int u; } c; c.f = x;
  unsigned int r = c.u + 0x7FFFu + ((c.u >> 16) & 1u);
  return (u16)(r >> 16);
}
__device__ __forceinline__ float aloadf(const float* p) {
  return __hip_atomic_load(p, __ATOMIC_RELAXED, __HIP_MEMORY_SCOPE_AGENT);
}
__device__ __forceinline__ void astoref(float* p, float v) {
  __hip_atomic_store(p, v, __ATOMIC_RELAXED, __HIP_MEMORY_SCOPE_AGENT);
}

// 8-block group barrier. flag points at a dedicated 256B-padded counter.
// Producers' data stores (agent-scope, cache-bypassing) are drained by each
// wave's own s_waitcnt before s_barrier (__syncthreads semantics), so the
// single tid-0 RELEASE add publishes everything. Poll RELAXED (no per-iter
// cache invalidation); one final ACQUIRE for the L1 invalidate.
__device__ __forceinline__ void sync8(int* flag) {
  __syncthreads();
  if (threadIdx.x == 0) {
    __hip_atomic_fetch_add(flag, 1, __ATOMIC_RELEASE, __HIP_MEMORY_SCOPE_AGENT);
    while (__hip_atomic_load(flag, __ATOMIC_RELAXED, __HIP_MEMORY_SCOPE_AGENT) < 8)
      __builtin_amdgcn_s_sleep(1);
    (void)__hip_atomic_load(flag, __ATOMIC_ACQUIRE, __HIP_MEMORY_SCOPE_AGENT);
  }
  __syncthreads();
}

// ---------------------------------------------------------------- conversions
__global__ void conv_bf(u16* __restrict__ dst, const float* __restrict__ src,
                        int n, int shift, int srcStride, int srcOff) {
  int i = blockIdx.x * 256 + threadIdx.x;
  if (i < n) {
    int r = i >> shift, c = i & ((1 << shift) - 1);
    dst[i] = f2b(src[(size_t)r * srcStride + srcOff + c]);
  }
}

__global__ void gather_emb(u16* __restrict__ dst, const float* __restrict__ emb,
                           const int* __restrict__ yin, int n) {
  int i = blockIdx.x * 256 + threadIdx.x;
  if (i < n) {
    int row = i >> 8, c = i & 255;
    int tok = yin[row];
    dst[i] = f2b(emb[(size_t)tok * HH + c]);
  }
}

__global__ void concat_hoc(u16* __restrict__ dst, const float* __restrict__ h_all,
                           const float* __restrict__ ctx_all, int n) {
  int i = blockIdx.x * 256 + threadIdx.x;
  if (i < n) {
    int row = i >> 9, c = i & 511;
    float v = (c < HH) ? h_all[(size_t)row * HH + c] : ctx_all[(size_t)row * HH + (c - HH)];
    dst[i] = f2b(v);
  }
}

// ---------------------------------------------------------------- generic GEMM
template <int AF32>
__global__ __launch_bounds__(256) void gemm_k(
    const void* __restrict__ Ap, const u16* __restrict__ W,
    const float* __restrict__ bias, void* __restrict__ Out,
    const int M, const int N, const int K, const int act, const int out_bf,
    float2* __restrict__ stats, const int ntiles) {
  __shared__ u16 sA[64 * 40];
  __shared__ u16 sB[64 * 40];
  const int tid = threadIdx.x;
  const int mt = blockIdx.x, nt = blockIdx.y;
  const int m0 = mt * 64, n0 = nt * 64;
  const int wave = tid >> 6, lane = tid & 63;
  const int quad = lane >> 4, l16 = lane & 15;
  const int r = tid >> 2, cc = (tid & 3) * 8;
  f32x4 acc[4] = {{0.f,0.f,0.f,0.f},{0.f,0.f,0.f,0.f},{0.f,0.f,0.f,0.f},{0.f,0.f,0.f,0.f}};

  for (int kk = 0; kk < K; kk += 32) {
    if (AF32) {
      const float* A = (const float*)Ap;
      const float* src = A + (size_t)(m0 + r) * K + kk + cc;
      const float4 v0 = *(const float4*)src;
      const float4 v1 = *(const float4*)(src + 4);
      u16* d = &sA[r * 40 + cc];
      d[0] = f2b(v0.x); d[1] = f2b(v0.y); d[2] = f2b(v0.z); d[3] = f2b(v0.w);
      d[4] = f2b(v1.x); d[5] = f2b(v1.y); d[6] = f2b(v1.z); d[7] = f2b(v1.w);
    } else {
      const u16* A = (const u16*)Ap;
      *(u16x8*)&sA[r * 40 + cc] = *(const u16x8*)(A + (size_t)(m0 + r) * K + kk + cc);
    }
    *(u16x8*)&sB[r * 40 + cc] = *(const u16x8*)(W + (size_t)(n0 + r) * K + kk + cc);
    __syncthreads();
    const s16x8 af = *(const s16x8*)&sA[(wave * 16 + l16) * 40 + quad * 8];
#pragma unroll
    for (int ns = 0; ns < 4; ++ns) {
      const s16x8 bf = *(const s16x8*)&sB[(ns * 16 + l16) * 40 + quad * 8];
      acc[ns] = __builtin_amdgcn_mfma_f32_16x16x32_bf16(af, bf, acc[ns], 0, 0, 0);
    }
    __syncthreads();
  }

  float vv[4][4];
#pragma unroll
  for (int ns = 0; ns < 4; ++ns) {
#pragma unroll
    for (int rr = 0; rr < 4; ++rr) {
      const int row = m0 + wave * 16 + quad * 4 + rr;
      const int col = n0 + ns * 16 + l16;
      float v = acc[ns][rr] + bias[col];
      if (act == 1) v = fmaxf(v, 0.f);
      else if (act == 2) v = tanhf(v);
      vv[ns][rr] = v;
      if (out_bf) ((u16*)Out)[(size_t)row * N + col] = f2b(v);
      else ((float*)Out)[(size_t)row * N + col] = v;
    }
  }
  if (stats) {
#pragma unroll
    for (int rr = 0; rr < 4; ++rr) {
      float mx = fmaxf(fmaxf(vv[0][rr], vv[1][rr]), fmaxf(vv[2][rr], vv[3][rr]));
#pragma unroll
      for (int off = 1; off < 16; off <<= 1) mx = fmaxf(mx, __shfl_xor(mx, off));
      float se = expf(vv[0][rr] - mx) + expf(vv[1][rr] - mx) +
                 expf(vv[2][rr] - mx) + expf(vv[3][rr] - mx);
#pragma unroll
      for (int off = 1; off < 16; off <<= 1) se += __shfl_xor(se, off);
      if (l16 == 0) {
        const int row = m0 + wave * 16 + quad * 4 + rr;
        stats[(size_t)row * ntiles + nt] = make_float2(mx, se);
      }
    }
  }
}

// ---------------------------------------------------------------- scan kernel
// 256 blocks. Swizzle: b = blockIdx%32, k = blockIdx/32 so the 8 collaborators
// of each b land on one XCD under round-robin dispatch (latency heuristic).
__global__ __launch_bounds__(256, 1) void scan_kernel(
    const float* __restrict__ y_enc, const u16* __restrict__ Wihc,
    const float* __restrict__ gw_hh, const float* __restrict__ gb_hh,
    const u16* __restrict__ f1w1b, const float* __restrict__ f1_b1,
    const float* __restrict__ f1_w2, const float* __restrict__ f1_b2,
    const u16* __restrict__ c2bf, const float* __restrict__ gi_emb,
    float* __restrict__ h_all, float* __restrict__ ctx_all,
    float* __restrict__ qp, float* __restrict__ part_m, float* __restrict__ part_l,
    float* __restrict__ part_ctx, int* __restrict__ cnt_h, int* __restrict__ cnt_att) {
  __shared__ u16 sYenc[128 * HH];   // 64 KB : y_enc[s-slice, b, :]
  __shared__ u16 sWhh[96 * HH];     // 48 KB : W_hh rows (r,z,n) of h-slice
  __shared__ u16 sF1w2[AA * HH];    // 32 KB
  __shared__ float sH[HH], sCtx[HH], sQ[HH];
  __shared__ float sHnew[32];
  __shared__ float sC1[AA];
  __shared__ float sP[128];
  __shared__ float sRed[32];

  const int tid = threadIdx.x;
  const int b = blockIdx.x & 31, k = blockIdx.x >> 5;

  for (int idx = tid; idx < 128 * HH; idx += 256) {
    int si = idx >> 8, m = idx & 255;
    sYenc[idx] = f2b(y_enc[((size_t)(k * 128 + si) * BB + b) * HH + m]);
  }
  for (int idx = tid; idx < 96 * HH; idx += 256) {
    int row = idx >> 8, m = idx & 255;
    int g = row >> 5, jj = row & 31;
    sWhh[idx] = f2b(gw_hh[(size_t)(g * HH + k * 32 + jj) * HH + m]);
  }
  for (int idx = tid; idx < AA * HH; idx += 256) sF1w2[idx] = f2b(f1_w2[idx]);
  if (tid < HH) { sH[tid] = 0.f; sCtx[tid] = 0.f; }
  __syncthreads();

  for (int t = 0; t < TT; ++t) {
    int* flagA = cnt_h + ((t * BB + b) << 6);   // 256B-padded counters
    int* flagB = cnt_att + ((t * BB + b) << 6);
    // ---------- Phase A: GRU h-slice ----------
    {
      const int jj = tid >> 3, p = tid & 7;
      const int jg = k * 32 + jj;
      const int mbase = p * 32;
      const u16* wbase = Wihc + (size_t)jg * HH + mbase;
      const u16* lbase = &sWhh[jj * HH + mbase];
      float ar = 0.f, az = 0.f, an = 0.f, br = 0.f, bz = 0.f, bn = 0.f;
#pragma unroll
      for (int ii = 0; ii < 8; ++ii) {
        const int i4 = ((ii + p) & 7) * 4;
        const float4 cm = *(const float4*)&sCtx[mbase + i4];
        const float4 hm = *(const float4*)&sH[mbase + i4];
        ushort4 wr = *(const ushort4*)(wbase + i4);
        ushort4 wz = *(const ushort4*)(wbase + 65536 + i4);
        ushort4 wn = *(const ushort4*)(wbase + 131072 + i4);
        ar += cm.x * b2f(wr.x) + cm.y * b2f(wr.y) + cm.z * b2f(wr.z) + cm.w * b2f(wr.w);
        az += cm.x * b2f(wz.x) + cm.y * b2f(wz.y) + cm.z * b2f(wz.z) + cm.w * b2f(wz.w);
        an += cm.x * b2f(wn.x) + cm.y * b2f(wn.y) + cm.z * b2f(wn.z) + cm.w * b2f(wn.w);
        ushort4 hr = *(const ushort4*)(lbase + i4);
        ushort4 hz = *(const ushort4*)(lbase + 32 * HH + i4);
        ushort4 hn = *(const ushort4*)(lbase + 64 * HH + i4);
        br += hm.x * b2f(hr.x) + hm.y * b2f(hr.y) + hm.z * b2f(hr.z) + hm.w * b2f(hr.w);
        bz += hm.x * b2f(hz.x) + hm.y * b2f(hz.y) + hm.z * b2f(hz.z) + hm.w * b2f(hz.w);
        bn += hm.x * b2f(hn.x) + hm.y * b2f(hn.y) + hm.z * b2f(hn.z) + hm.w * b2f(hn.w);
      }
#pragma unroll
      for (int off = 1; off < 8; off <<= 1) {
        ar += __shfl_xor(ar, off); az += __shfl_xor(az, off); an += __shfl_xor(an, off);
        br += __shfl_xor(br, off); bz += __shfl_xor(bz, off); bn += __shfl_xor(bn, off);
      }
      if (p == 0) {
        const float* ge = gi_emb + (size_t)(t * BB + b) * 768;
        float gr = ar + ge[jg];
        float gz = az + ge[256 + jg];
        float gn = an + ge[512 + jg];
        float hr2 = br + gb_hh[jg];
        float hz2 = bz + gb_hh[256 + jg];
        float hn2 = bn + gb_hh[512 + jg];
        float r_ = 1.f / (1.f + expf(-(gr + hr2)));
        float z_ = 1.f / (1.f + expf(-(gz + hz2)));
        float n_ = tanhf(gn + r_ * hn2);
        float hnw = (1.f - z_) * n_ + z_ * sH[jg];
        sHnew[jj] = hnw;
        astoref(&h_all[(size_t)(t * BB + b) * HH + jg], hnw);
      }
    }
    __syncthreads();
    // layer1 partial contribution of this h-slice (linear, pre-relu)
    {
      float q = 0.f;
      const u16* wrow = f1w1b + (size_t)tid * HH + k * 32;
#pragma unroll
      for (int j4 = 0; j4 < 32; j4 += 4) {
        ushort4 w4 = *(const ushort4*)(wrow + j4);
        q += sHnew[j4] * b2f(w4.x) + sHnew[j4 + 1] * b2f(w4.y) +
             sHnew[j4 + 2] * b2f(w4.z) + sHnew[j4 + 3] * b2f(w4.w);
      }
      astoref(&qp[(size_t)(b * 8 + k) * HH + tid], q);
    }
    sync8(flagA);
    // ---------- Phase A': gather h, layer1 sum+relu, c1 ----------
    sH[tid] = aloadf(&h_all[(size_t)(t * BB + b) * HH + tid]);
    {
      float qq = f1_b1[tid];
#pragma unroll
      for (int k2 = 0; k2 < 8; ++k2) qq += aloadf(&qp[(size_t)(b * 8 + k2) * HH + tid]);
      sQ[tid] = fmaxf(qq, 0.f);
    }
    __syncthreads();
    {
      const int a = tid >> 2, p4 = tid & 3;
      float s = 0.f;
      const u16* wa = &sF1w2[a * HH];
#pragma unroll
      for (int ii = 0; ii < 16; ++ii) {
        const int i4 = (((ii + a) & 15) * 4) + p4 * 64;
        ushort4 w4 = *(const ushort4*)(wa + i4);
        s += sQ[i4] * b2f(w4.x) + sQ[i4 + 1] * b2f(w4.y) +
             sQ[i4 + 2] * b2f(w4.z) + sQ[i4 + 3] * b2f(w4.w);
      }
      s += __shfl_xor(s, 1);
      s += __shfl_xor(s, 2);
      if (p4 == 0) sC1[a] = tanhf(s + f1_b2[a]);
    }
    __syncthreads();
    // ---------- Phase B: scores + online softmax + ctx partial ----------
    if (tid < 128) {
      const int sg = k * 128 + tid;
      const u16* c2r = c2bf + (size_t)(sg * BB + b) * AA;
      float sc = 0.f;
#pragma unroll
      for (int a4 = 0; a4 < AA; a4 += 4) {
        ushort4 c4 = *(const ushort4*)(c2r + a4);
        sc += sC1[a4] * b2f(c4.x) + sC1[a4 + 1] * b2f(c4.y) +
              sC1[a4 + 2] * b2f(c4.z) + sC1[a4 + 3] * b2f(c4.w);
      }
      sP[tid] = sc;
    }
    __syncthreads();
    {
      float v = (tid < 64) ? fmaxf(sP[tid], sP[tid + 64]) : -3e38f;
#pragma unroll
      for (int off = 1; off < 64; off <<= 1) v = fmaxf(v, __shfl_xor(v, off));
      if (tid == 0) sRed[0] = v;
    }
    __syncthreads();
    const float mloc = sRed[0];
    {
      float e = 0.f;
      if (tid < 128) { e = expf(sP[tid] - mloc); sP[tid] = e; }
#pragma unroll
      for (int off = 1; off < 64; off <<= 1) e += __shfl_xor(e, off);
      if ((tid & 63) == 0) sRed[1 + (tid >> 6)] = e;
    }
    __syncthreads();
    {
      float accm = 0.f;
#pragma unroll 8
      for (int si = 0; si < 128; ++si) accm += sP[si] * b2f(sYenc[si * HH + tid]);
      astoref(&part_ctx[(size_t)(b * 8 + k) * HH + tid], accm);
      if (tid == 0) {
        astoref(&part_m[b * 8 + k], mloc);
        astoref(&part_l[b * 8 + k], sRed[1] + sRed[2] + sRed[3] + sRed[4]);
      }
    }
    sync8(flagB);
    // ---------- Phase B': combine 8 online-softmax partials ----------
    if (tid < 8) {
      sRed[16 + tid] = aloadf(&part_m[b * 8 + tid]);
      sRed[24 + tid] = aloadf(&part_l[b * 8 + tid]);
    }
    __syncthreads();
    {
      float M = -3e38f;
#pragma unroll
      for (int k2 = 0; k2 < 8; ++k2) M = fmaxf(M, sRed[16 + k2]);
      float L = 0.f;
      float w8[8];
#pragma unroll
      for (int k2 = 0; k2 < 8; ++k2) {
        float e = expf(sRed[16 + k2] - M);
        w8[k2] = e;
        L += sRed[24 + k2] * e;
      }
      const float inv = 1.f / L;
      float cx = 0.f;
#pragma unroll
      for (int k2 = 0; k2 < 8; ++k2)
        cx += w8[k2] * aloadf(&part_ctx[(size_t)(b * 8 + k2) * HH + tid]);
      cx *= inv;
      sCtx[tid] = cx;
      ctx_all[(size_t)(t * BB + b) * HH + tid] = cx;
    }
    __syncthreads();
  }
}

// ---------------------------------------------------------------- loss
__global__ __launch_bounds__(256) void loss_rows(
    const float2* __restrict__ stats, const float* __restrict__ preds,
    const int* __restrict__ tgt, float* __restrict__ accum, int ntiles) {
  const int row = blockIdx.x, tid = threadIdx.x;
  float m = -3e38f, l = 0.f;
  for (int j = tid; j < ntiles; j += 256) {
    float2 s = stats[(size_t)row * ntiles + j];
    if (s.x > m) { l = l * expf(m - s.x) + s.y; m = s.x; }
    else l += s.y * expf(s.x - m);
  }
  __shared__ float sm[256], sl[256];
  sm[tid] = m; sl[tid] = l;
  __syncthreads();
  for (int off = 128; off; off >>= 1) {
    if (tid < off) {
      float m2 = sm[tid + off], l2 = sl[tid + off];
      float M = fmaxf(sm[tid], m2);
      sl[tid] = sl[tid] * expf(sm[tid] - M) + l2 * expf(m2 - M);
      sm[tid] = M;
    }
    __syncthreads();
  }
  if (tid == 0) {
    int t = tgt[row];
    float lse = sm[0] + logf(sl[0]);
    float nll = lse - preds[(size_t)row * VV + t];
    if (t != 0) {
      atomicAdd(&accum[0], nll);
      atomicAdd(&accum[1], 1.f);
    }
  }
}

__global__ void finalize_k(const float* __restrict__ accum, float* __restrict__ out) {
  out[0] = accum[0] / fmaxf(accum[1], 1.f);
}

// ---------------------------------------------------------------- launcher
extern "C" void kernel_launch(void* const* d_in, const int* in_sizes, int n_in,
                              void* d_out, int out_size, void* d_ws, size_t ws_size,
                              hipStream_t stream) {
  (void)in_sizes; (void)n_in; (void)out_size; (void)ws_size;
  const int* y_in = (const int*)d_in[0];
  const int* y_out = (const int*)d_in[1];
  const float* y_enc = (const float*)d_in[2];
  const float* emb = (const float*)d_in[4];
  const float* f1_w1 = (const float*)d_in[5];
  const float* f1_b1 = (const float*)d_in[6];
  const float* f1_w2 = (const float*)d_in[7];
  const float* f1_b2 = (const float*)d_in[8];
  const float* f2_w1 = (const float*)d_in[9];
  const float* f2_b1 = (const float*)d_in[10];
  const float* f2_w2 = (const float*)d_in[11];
  const float* f2_b2 = (const float*)d_in[12];
  const float* gw_ih = (const float*)d_in[13];
  const float* gb_ih = (const float*)d_in[14];
  const float* gw_hh = (const float*)d_in[15];
  const float* gb_hh = (const float*)d_in[16];
  const float* fc1_w = (const float*)d_in[17];
  const float* fc1_b = (const float*)d_in[18];
  const float* fc2_w = (const float*)d_in[19];
  const float* fc2_b = (const float*)d_in[20];
  float* out = (float*)d_out;

  char* w = (char*)d_ws;
  auto alloc = [&](size_t bytes) {
    char* p = w;
    w += (bytes + 255) & ~(size_t)255;
    return p;
  };
  int* cnt_h = (int*)alloc((size_t)TT * BB * 64 * 4);    // 512 KB (256B-padded flags)
  int* cnt_att = (int*)alloc((size_t)TT * BB * 64 * 4);  // 512 KB
  float* accum = (float*)alloc(256);
  float* gi_emb = (float*)alloc((size_t)2048 * 768 * 4);
  float* h_all = (float*)alloc((size_t)2048 * HH * 4);
  float* ctx_all = (float*)alloc((size_t)2048 * HH * 4);
  float* qp = (float*)alloc((size_t)BB * 8 * HH * 4);
  float* part_m = (float*)alloc(1024);
  float* part_l = (float*)alloc(1024);
  float* part_ctx = (float*)alloc((size_t)BB * 8 * HH * 4);
  u16* c2_bf = (u16*)alloc((size_t)SS * BB * AA * 2);
  u16* Wihe = (u16*)alloc((size_t)768 * HH * 2);
  u16* Wihc = (u16*)alloc((size_t)768 * HH * 2);
  u16* f2w1b = (u16*)alloc((size_t)HH * HH * 2);
  u16* f2w2b = (u16*)alloc((size_t)AA * HH * 2);
  u16* f1w1b = (u16*)alloc((size_t)HH * HH * 2);
  u16* fc1wb = (u16*)alloc((size_t)HH * 512 * 2);
  u16* fc2wb = (u16*)alloc((size_t)VV * HH * 2);
  u16* aembb = (u16*)alloc((size_t)2048 * HH * 2);
  u16* z1 = (u16*)alloc((size_t)2048 * HH * 2);
  u16* hocb = (u16*)alloc((size_t)2048 * 512 * 2);
  char* tmp_region = alloc((size_t)32768 * 256 * 2);  // tmp1 (bf16), later stats
  u16* tmp1 = (u16*)tmp_region;
  float2* stats = (float2*)tmp_region;  // 2048*500*8 = 8.2MB <= 16.8MB

  // zero the two padded flag arrays + accum
  hipMemsetAsync(d_ws, 0, (size_t)TT * BB * 64 * 4 * 2 + 512, stream);

  // weight conversions
  conv_bf<<<dim3(256), dim3(256), 0, stream>>>(f2w1b, f2_w1, 65536, 8, 256, 0);
  conv_bf<<<dim3(64), dim3(256), 0, stream>>>(f2w2b, f2_w2, 16384, 8, 256, 0);
  conv_bf<<<dim3(768), dim3(256), 0, stream>>>(Wihe, gw_ih, 196608, 8, 512, 0);
  conv_bf<<<dim3(768), dim3(256), 0, stream>>>(Wihc, gw_ih, 196608, 8, 512, 256);
  conv_bf<<<dim3(256), dim3(256), 0, stream>>>(f1w1b, f1_w1, 65536, 8, 256, 0);
  conv_bf<<<dim3(512), dim3(256), 0, stream>>>(fc1wb, fc1_w, 131072, 9, 512, 0);
  conv_bf<<<dim3(32000), dim3(256), 0, stream>>>(fc2wb, fc2_w, 8192000, 8, 256, 0);
  gather_emb<<<dim3(2048), dim3(256), 0, stream>>>(aembb, emb, y_in, 2048 * 256);

  // gi_emb = emb_gathered @ W_ih[:, :256]^T + b_ih   [2048, 768]
  gemm_k<0><<<dim3(32, 12), dim3(256), 0, stream>>>(
      aembb, Wihe, gb_ih, gi_emb, 2048, 768, 256, 0, 0, nullptr, 0);
  // tmp1 = relu(y_enc @ f2_w1^T + b1)   [32768, 256] bf16
  gemm_k<1><<<dim3(512, 4), dim3(256), 0, stream>>>(
      y_enc, f2w1b, f2_b1, tmp1, 32768, 256, 256, 1, 1, nullptr, 0);
  // c2 = tanh(tmp1 @ f2_w2^T + b2)   [32768, 64] bf16
  gemm_k<0><<<dim3(512, 1), dim3(256), 0, stream>>>(
      tmp1, f2w2b, f2_b2, c2_bf, 32768, 64, 256, 2, 1, nullptr, 0);

  // sequential scan: 64 steps, persistent blocks, per-b flag sync
  scan_kernel<<<dim3(256), dim3(256), 0, stream>>>(
      y_enc, Wihc, gw_hh, gb_hh, f1w1b, f1_b1, f1_w2, f1_b2, c2_bf, gi_emb,
      h_all, ctx_all, qp, part_m, part_l, part_ctx, cnt_h, cnt_att);

  // output head
  concat_hoc<<<dim3(4096), dim3(256), 0, stream>>>(hocb, h_all, ctx_all, 2048 * 512);
  gemm_k<0><<<dim3(32, 4), dim3(256), 0, stream>>>(
      hocb, fc1wb, fc1_b, z1, 2048, 256, 512, 1, 1, nullptr, 0);
  gemm_k<0><<<dim3(32, 500), dim3(256), 0, stream>>>(
      z1, fc2wb, fc2_b, out, 2048, VV, 256, 0, 0, stats, 500);

  // masked mean NLL from per-tile softmax stats
  loss_rows<<<dim3(2048), dim3(256), 0, stream>>>(stats, out, y_out, accum, 500);
  finalize_k<<<dim3(1), dim3(1), 0, stream>>>(accum, out + (size_t)TT * BB * VV);
}